// Round 8
// baseline (246.215 us; speedup 1.0000x reference)
//
#include <hip/hip_runtime.h>
#include <cstdint>

#define NN 4096
#define DD 128
#define NB 16

typedef __attribute__((ext_vector_type(8))) short short8;
typedef __attribute__((ext_vector_type(4))) float f32x4;
typedef __attribute__((ext_vector_type(2))) float f32x2;
typedef unsigned short u16;

// fold scale (1/sqrt(D)) and log2(e) into everything once:
#define S2 (0.088388347648318447f * 1.4426950408889634f)

static __device__ __forceinline__ f32x2 pkfma(f32x2 a, f32x2 b, f32x2 c) {
#if __has_builtin(__builtin_elementwise_fma)
  return __builtin_elementwise_fma(a, b, c);   // -> v_pk_fma_f32
#else
  return a * b + c;
#endif
}

__device__ __forceinline__ u16 f2bf(float f) {
  union { float f; unsigned int u; } v; v.f = f;
  unsigned int u = v.u;
  u += 0x7fffu + ((u >> 16) & 1u);   // round-to-nearest-even
  return (u16)(u >> 16);
}

// ---------------------------------------------------------------------------
// Kernel 1: per-row precompute (unchanged — verified rounds 3-6).
//   Qbh[r][d] = bf16( (q_b[d]+pe[r][d]) * S2 )
//   Kbh[r][d] = bf16(  k_b[d]+pe[r][d] )
//   A2[r] = S2 * q_w·(k_b+pe_r),  B2[r] = S2 * k_w·(q_b+pe_r),  c2 = S2 * q_w·k_w
// ---------------------------------------------------------------------------
__global__ void precomp_kernel(const float* __restrict__ q_w, const float* __restrict__ q_b,
                               const float* __restrict__ k_w, const float* __restrict__ k_b,
                               const float* __restrict__ pe,
                               u16* __restrict__ Qbh, u16* __restrict__ Kbh,
                               float* __restrict__ A2, float* __restrict__ B2,
                               float* __restrict__ c2p) {
  const int t = threadIdx.x, lane = t & 63, wv = t >> 6;
  const int row = blockIdx.x * 4 + wv;

  const float p0 = pe[row * DD + lane];
  const float p1 = pe[row * DD + 64 + lane];
  const float qv0 = q_b[lane] + p0, qv1 = q_b[lane + 64] + p1;
  const float kv0 = k_b[lane] + p0, kv1 = k_b[lane + 64] + p1;
  const float qw0 = q_w[lane], qw1 = q_w[lane + 64];
  const float kw0 = k_w[lane], kw1 = k_w[lane + 64];

  Qbh[row * DD + lane]      = f2bf(qv0 * S2);
  Qbh[row * DD + 64 + lane] = f2bf(qv1 * S2);
  Kbh[row * DD + lane]      = f2bf(kv0);
  Kbh[row * DD + 64 + lane] = f2bf(kv1);

  float asum = qw0 * kv0 + qw1 * kv1;
  float bsum = kw0 * qv0 + kw1 * qv1;
#pragma unroll
  for (int m = 1; m < 64; m <<= 1) {
    asum += __shfl_xor(asum, m);
    bsum += __shfl_xor(bsum, m);
  }
  if (lane == 0) { A2[row] = S2 * asum; B2[row] = S2 * bsum; }

  if (row == 0) {
    float csum = qw0 * kw0 + qw1 * kw1;
#pragma unroll
    for (int m = 1; m < 64; m <<= 1) csum += __shfl_xor(csum, m);
    if (lane == 0) *c2p = S2 * csum;
  }
}

// ---------------------------------------------------------------------------
// Kernel 2: main. Grid (NN/16, JSPLIT), 256 threads (4 waves), waves split j.
// CLEAN HOT LOOP (the round-5/6 synthesis): per b-iter only
//   5 LDS broadcast reads (4 xv + 1 xib, conflict-free) + 32 pk + 16 exp2,
// accumulating into l[16]/o[16] REGISTERS. No global loads, no shuffles,
// no LDS writes inside the loop; h-reduction once in the epilogue.
//   s = xj*Vb + (xi*A2_j + M_ij),  Vb = c2*xi + B2_i
//   p = exp2(s);  l += p;  o += p*xj
// ---------------------------------------------------------------------------
template <int JSPLIT>
__global__ __launch_bounds__(256, 4) void attn_main(
    const float* __restrict__ x, const u16* __restrict__ Qbh,
    const u16* __restrict__ Kbh, const float* __restrict__ A2,
    const float* __restrict__ B2, const float* __restrict__ c2p,
    float* __restrict__ part_l, float* __restrict__ part_o) {
  constexpr int JRANGE = NN / JSPLIT;
  constexpr int NSEG = JRANGE / 256;

  __shared__ __align__(16) float xs[16 * 256];  // x segment [b][256 j]
  __shared__ __align__(16) float a2s[256];      // A2 segment
  __shared__ __align__(16) float xis[256];      // x[b][i-tile]: [b][16 i]
  __shared__ __align__(16) float red[2048];     // [l/o][w][b][i]

  const int t = threadIdx.x;
  const int lane = t & 63, w = t >> 6;
  const int il = lane & 15, h = lane >> 4;
  const int i0 = blockIdx.x * 16;
  const int js = blockIdx.y;
  const int jb = js * JRANGE;

  const float c2 = *c2p;
  const float B2i = B2[i0 + il];

  // stage x[b][i-tile] once (16 b x 16 i = 1 KB)
  xis[t] = x[(t >> 4) * NN + i0 + (t & 15)];

  // Q fragments (B-operand), loaded once.
  short8 qfr[4];
#pragma unroll
  for (int ks = 0; ks < 4; ++ks)
    qfr[ks] = *(const short8*)(Qbh + (i0 + il) * DD + ks * 32 + h * 8);

  float l[16], o[16];
#pragma unroll
  for (int b = 0; b < 16; ++b) { l[b] = 0.f; o[b] = 0.f; }

  for (int seg = 0; seg < NSEG; ++seg) {
    const int j0 = jb + seg * 256;
    __syncthreads();  // previous segment fully consumed before restage
#pragma unroll
    for (int it = 0; it < 4; ++it) {
      const int flat = it * 256 + t;          // 0..1023 float4
      const int b = flat >> 6, c4 = flat & 63;
      *(float4*)(&xs[b * 256 + c4 * 4]) =
          *(const float4*)(x + b * NN + j0 + c4 * 4);
    }
    if (t < 64)
      *(float4*)(&a2s[t * 4]) = *(const float4*)(A2 + j0 + t * 4);
    __syncthreads();

    // --- MFMA phase: 4 chunks for this wave's 64-j window ---
    f32x4 acc[4];
    {
      const u16* kb = Kbh + (j0 + w * 64 + il) * DD + h * 8;
#pragma unroll
      for (int c = 0; c < 4; ++c) {
        short8 kfr[4];
#pragma unroll
        for (int ks = 0; ks < 4; ++ks)
          kfr[ks] = *(const short8*)(kb + c * 16 * DD + ks * 32);
        f32x4 a = {0.f, 0.f, 0.f, 0.f};
#pragma unroll
        for (int ks = 0; ks < 4; ++ks)
          a = __builtin_amdgcn_mfma_f32_16x16x32_bf16(kfr[ks], qfr[ks], a, 0, 0, 0);
        acc[c] = a;   // i = il, j = j0 + w*64 + c*16 + 4h + v
      }
    }

    float4 a2v[4];
#pragma unroll
    for (int c = 0; c < 4; ++c)
      a2v[c] = *(const float4*)(&a2s[w * 64 + c * 16 + 4 * h]);

    const float* xw = &xs[w * 64 + 4 * h];
    const float* xib_p = &xis[il];

#pragma unroll
    for (int b = 0; b < 16; ++b) {
      const float xic = xib_p[b * 16];                 // LDS broadcast
      const f32x2 xib = {xic, xic};
      const float Vb = fmaf(c2, xic, B2i);
      const f32x2 Vb2 = {Vb, Vb};
      f32x2 l2 = {0.f, 0.f}, o2 = {0.f, 0.f};
#pragma unroll
      for (int c = 0; c < 4; ++c) {
        const float4 xv = *(const float4*)(xw + b * 256 + c * 16);  // broadcast
        const f32x2 xv01 = {xv.x, xv.y}, xv23 = {xv.z, xv.w};
        const f32x2 alo = {a2v[c].x, a2v[c].y}, ahi = {a2v[c].z, a2v[c].w};
        const f32x2 clo = {acc[c][0], acc[c][1]}, chi = {acc[c][2], acc[c][3]};
        const f32x2 s01 = pkfma(xv01, Vb2, pkfma(xib, alo, clo));
        const f32x2 s23 = pkfma(xv23, Vb2, pkfma(xib, ahi, chi));
        const f32x2 e01 = {__builtin_amdgcn_exp2f(s01[0]),
                           __builtin_amdgcn_exp2f(s01[1])};
        const f32x2 e23 = {__builtin_amdgcn_exp2f(s23[0]),
                           __builtin_amdgcn_exp2f(s23[1])};
        l2 += e01; l2 += e23;
        o2 = pkfma(e01, xv01, o2);
        o2 = pkfma(e23, xv23, o2);
      }
      l[b] += l2[0] + l2[1];
      o[b] += o2[0] + o2[1];
    }
  }

  // --- epilogue: reduce over h once, then across waves ---
#pragma unroll
  for (int b = 0; b < 16; ++b) {
    float lv = l[b], ov = o[b];
    lv += __shfl_xor(lv, 16); lv += __shfl_xor(lv, 32);
    ov += __shfl_xor(ov, 16); ov += __shfl_xor(ov, 32);
    if (h == 0) {
      red[(w * 16 + b) * 16 + il]        = lv;
      red[1024 + (w * 16 + b) * 16 + il] = ov;
    }
  }
  __syncthreads();

  {
    const int b = t >> 4, ii = t & 15;
    float lsum = 0.f, osum = 0.f;
#pragma unroll
    for (int ww = 0; ww < 4; ++ww) {
      lsum += red[(ww * 16 + b) * 16 + ii];
      osum += red[1024 + (ww * 16 + b) * 16 + ii];
    }
    const int outidx = (js * NB + b) * NN + i0 + ii;
    part_l[outidx] = lsum;
    part_o[outidx] = osum;
  }
}

// ---------------------------------------------------------------------------
// Kernel 3: deterministic combine of the JSPLIT partial sums; out = Σo / Σl.
// ---------------------------------------------------------------------------
template <int JSPLIT>
__global__ void combine_kernel(const float* __restrict__ part_l,
                               const float* __restrict__ part_o,
                               float* __restrict__ out) {
  const int id = blockIdx.x * 256 + threadIdx.x;  // b*NN + i
  float l = 0.f, o = 0.f;
#pragma unroll
  for (int js = 0; js < JSPLIT; ++js) {
    l += part_l[js * (NB * NN) + id];
    o += part_o[js * (NB * NN) + id];
  }
  out[id] = o / l;
}

extern "C" void kernel_launch(void* const* d_in, const int* in_sizes, int n_in,
                              void* d_out, int out_size, void* d_ws, size_t ws_size,
                              hipStream_t stream) {
  const float* x   = (const float*)d_in[0];
  const float* q_w = (const float*)d_in[1];
  const float* q_b = (const float*)d_in[2];
  const float* k_w = (const float*)d_in[3];
  const float* k_b = (const float*)d_in[4];
  const float* pe  = (const float*)d_in[5];
  float* out = (float*)d_out;

  char* ws = (char*)d_ws;
  u16*   Qbh    = (u16*)(ws);                                    // 1 MB
  u16*   Kbh    = (u16*)(ws + (1u << 20));                       // 1 MB
  float* A2     = (float*)(ws + (2u << 20));                     // 16 KB
  float* B2     = (float*)(ws + (2u << 20) + (16u << 10));       // 16 KB
  float* c2p    = (float*)(ws + (2u << 20) + (32u << 10));       // 64 B
  float* part_l = (float*)(ws + (2u << 20) + (48u << 10));

  precomp_kernel<<<NN / 4, 256, 0, stream>>>(q_w, q_b, k_w, k_b, pe,
                                             Qbh, Kbh, A2, B2, c2p);

  const size_t base = (size_t)(2u << 20) + (48u << 10);
  const size_t need16 = base + 2 * (size_t)16 * NB * NN * 4;  // ~10.4 MB
  if (ws_size >= need16) {
    float* part_o = (float*)(ws + base + (size_t)16 * NB * NN * 4);
    attn_main<16><<<dim3(NN / 16, 16), 256, 0, stream>>>(
        x, Qbh, Kbh, A2, B2, c2p, part_l, part_o);
    combine_kernel<16><<<(NB * NN) / 256, 256, 0, stream>>>(part_l, part_o, out);
  } else {
    float* part_o = (float*)(ws + base + (size_t)8 * NB * NN * 4);
    attn_main<8><<<dim3(NN / 16, 8), 256, 0, stream>>>(
        x, Qbh, Kbh, A2, B2, c2p, part_l, part_o);
    combine_kernel<8><<<(NB * NN) / 256, 256, 0, stream>>>(part_l, part_o, out);
  }
}

// Round 9
// 65.352 us; speedup vs baseline: 3.7675x; 3.7675x over previous
//
#include <hip/hip_runtime.h>
#include <cstdint>

#define NN 4096
#define DD 128
#define NB 16

typedef __attribute__((ext_vector_type(8))) short short8;
typedef __attribute__((ext_vector_type(4))) float f32x4;
typedef __attribute__((ext_vector_type(2))) float f32x2;
typedef unsigned short u16;

// fold scale (1/sqrt(D)) and log2(e) into everything once:
#define S2 (0.088388347648318447f * 1.4426950408889634f)

static __device__ __forceinline__ f32x2 pkfma(f32x2 a, f32x2 b, f32x2 c) {
#if __has_builtin(__builtin_elementwise_fma)
  return __builtin_elementwise_fma(a, b, c);   // -> v_pk_fma_f32
#else
  return a * b + c;
#endif
}

__device__ __forceinline__ u16 f2bf(float f) {
  union { float f; unsigned int u; } v; v.f = f;
  unsigned int u = v.u;
  u += 0x7fffu + ((u >> 16) & 1u);   // round-to-nearest-even
  return (u16)(u >> 16);
}

// ---------------------------------------------------------------------------
// Kernel 1: per-row precompute (unchanged — verified rounds 3-7).
//   Qbh[r][d] = bf16( (q_b[d]+pe[r][d]) * S2 )
//   Kbh[r][d] = bf16(  k_b[d]+pe[r][d] )
//   A2[r] = S2 * q_w·(k_b+pe_r),  B2[r] = S2 * k_w·(q_b+pe_r),  c2 = S2 * q_w·k_w
// ---------------------------------------------------------------------------
__global__ void precomp_kernel(const float* __restrict__ q_w, const float* __restrict__ q_b,
                               const float* __restrict__ k_w, const float* __restrict__ k_b,
                               const float* __restrict__ pe,
                               u16* __restrict__ Qbh, u16* __restrict__ Kbh,
                               float* __restrict__ A2, float* __restrict__ B2,
                               float* __restrict__ c2p) {
  const int t = threadIdx.x, lane = t & 63, wv = t >> 6;
  const int row = blockIdx.x * 4 + wv;

  const float p0 = pe[row * DD + lane];
  const float p1 = pe[row * DD + 64 + lane];
  const float qv0 = q_b[lane] + p0, qv1 = q_b[lane + 64] + p1;
  const float kv0 = k_b[lane] + p0, kv1 = k_b[lane + 64] + p1;
  const float qw0 = q_w[lane], qw1 = q_w[lane + 64];
  const float kw0 = k_w[lane], kw1 = k_w[lane + 64];

  Qbh[row * DD + lane]      = f2bf(qv0 * S2);
  Qbh[row * DD + 64 + lane] = f2bf(qv1 * S2);
  Kbh[row * DD + lane]      = f2bf(kv0);
  Kbh[row * DD + 64 + lane] = f2bf(kv1);

  float asum = qw0 * kv0 + qw1 * kv1;
  float bsum = kw0 * qv0 + kw1 * qv1;
#pragma unroll
  for (int m = 1; m < 64; m <<= 1) {
    asum += __shfl_xor(asum, m);
    bsum += __shfl_xor(bsum, m);
  }
  if (lane == 0) { A2[row] = S2 * asum; B2[row] = S2 * bsum; }

  if (row == 0) {
    float csum = qw0 * kw0 + qw1 * kw1;
#pragma unroll
    for (int m = 1; m < 64; m <<= 1) csum += __shfl_xor(csum, m);
    if (lane == 0) *c2p = S2 * csum;
  }
}

// ---------------------------------------------------------------------------
// Kernel 2: main. Grid (NN/16, JSPLIT), 256 threads (4 waves), waves split j.
// ROUND-6 STRUCTURE (44 VGPR, no spill) + two register-cheap fixes:
//  * xi from a 1 KB LDS tile (broadcast read) instead of per-b global prefetch
//  * h-reduction deferred: lv/ov for 4 b's batched, 8 shfl chains interleaved
//    once per 4 b-iters (amortizes the 2-deep cross-lane latency 4x).
// Live state through the hot loop: acc[4] (16) + a2v[4] (16) + lvv/ovv (8)
// + scalars ~= 52 VGPR  — deliberately under the ~64 spill cliff (round-7
// post-mortem: exceeding it cost 1.1 GB/dispatch of scratch traffic).
//   s = xj*Vb + (xi*A2_j + M_ij),  Vb = c2*xi + B2_i     (packed f32)
//   p = exp2(s);  l += p;  o += p*xj
// ---------------------------------------------------------------------------
template <int JSPLIT>
__global__ __launch_bounds__(256, 5) void attn_main(
    const float* __restrict__ x, const u16* __restrict__ Qbh,
    const u16* __restrict__ Kbh, const float* __restrict__ A2,
    const float* __restrict__ B2, const float* __restrict__ c2p,
    float* __restrict__ part_l, float* __restrict__ part_o) {
  constexpr int JRANGE = NN / JSPLIT;
  constexpr int NSEG = JRANGE / 256;

  __shared__ __align__(16) float xs[16 * 256];  // x segment [b][256 j]
  __shared__ __align__(16) float a2s[256];      // A2 segment
  __shared__ __align__(16) float xis[256];      // x[b][i-tile]: [b][16 i]
  __shared__ __align__(16) float red[2048];     // [l/o][w][b][i]

  const int t = threadIdx.x;
  const int lane = t & 63, w = t >> 6;
  const int il = lane & 15, h = lane >> 4;
  const int i0 = blockIdx.x * 16;
  const int js = blockIdx.y;
  const int jb = js * JRANGE;

  const float c2 = *c2p;
  const float B2i = B2[i0 + il];

  // stage x[b][i-tile] once (16 b x 16 i = 1 KB)
  xis[t] = x[(t >> 4) * NN + i0 + (t & 15)];

  // Q fragments (B-operand), loaded once.
  short8 qfr[4];
#pragma unroll
  for (int ks = 0; ks < 4; ++ks)
    qfr[ks] = *(const short8*)(Qbh + (i0 + il) * DD + ks * 32 + h * 8);

  for (int seg = 0; seg < NSEG; ++seg) {
    const int j0 = jb + seg * 256;
    __syncthreads();  // previous segment consumed (and xis staged) before use
#pragma unroll
    for (int it = 0; it < 4; ++it) {
      const int flat = it * 256 + t;          // 0..1023 float4
      const int b = flat >> 6, c4 = flat & 63;
      *(float4*)(&xs[b * 256 + c4 * 4]) =
          *(const float4*)(x + b * NN + j0 + c4 * 4);
    }
    if (t < 64)
      *(float4*)(&a2s[t * 4]) = *(const float4*)(A2 + j0 + t * 4);
    __syncthreads();

    // --- MFMA phase: 4 chunks for this wave's 64-j window ---
    f32x4 acc[4];
    {
      const u16* kb = Kbh + (j0 + w * 64 + il) * DD + h * 8;
#pragma unroll
      for (int c = 0; c < 4; ++c) {
        short8 kfr[4];
#pragma unroll
        for (int ks = 0; ks < 4; ++ks)
          kfr[ks] = *(const short8*)(kb + c * 16 * DD + ks * 32);
        f32x4 a = {0.f, 0.f, 0.f, 0.f};
#pragma unroll
        for (int ks = 0; ks < 4; ++ks)
          a = __builtin_amdgcn_mfma_f32_16x16x32_bf16(kfr[ks], qfr[ks], a, 0, 0, 0);
        acc[c] = a;   // i = il, j = j0 + w*64 + c*16 + 4h + v
      }
    }

    float4 a2v[4];
#pragma unroll
    for (int c = 0; c < 4; ++c)
      a2v[c] = *(const float4*)(&a2s[w * 64 + c * 16 + 4 * h]);

    const float* xw = &xs[w * 64 + 4 * h];
    const float* xib_p = &xis[il];

#pragma unroll
    for (int b4 = 0; b4 < 16; b4 += 4) {
      float lvv[4], ovv[4];
#pragma unroll
      for (int bb = 0; bb < 4; ++bb) {
        const int b = b4 + bb;
        const float xic = xib_p[b * 16];               // LDS broadcast
        const f32x2 xib = {xic, xic};
        const float Vb = fmaf(c2, xic, B2i);
        const f32x2 Vb2 = {Vb, Vb};
        f32x2 l2 = {0.f, 0.f}, o2 = {0.f, 0.f};
#pragma unroll
        for (int c = 0; c < 4; ++c) {
          const float4 xv = *(const float4*)(xw + b * 256 + c * 16);  // broadcast
          const f32x2 xv01 = {xv.x, xv.y}, xv23 = {xv.z, xv.w};
          const f32x2 alo = {a2v[c].x, a2v[c].y}, ahi = {a2v[c].z, a2v[c].w};
          const f32x2 clo = {acc[c][0], acc[c][1]}, chi = {acc[c][2], acc[c][3]};
          const f32x2 s01 = pkfma(xv01, Vb2, pkfma(xib, alo, clo));
          const f32x2 s23 = pkfma(xv23, Vb2, pkfma(xib, ahi, chi));
          const f32x2 e01 = {__builtin_amdgcn_exp2f(s01[0]),
                             __builtin_amdgcn_exp2f(s01[1])};
          const f32x2 e23 = {__builtin_amdgcn_exp2f(s23[0]),
                             __builtin_amdgcn_exp2f(s23[1])};
          l2 += e01; l2 += e23;
          o2 = pkfma(e01, xv01, o2);
          o2 = pkfma(e23, xv23, o2);
        }
        lvv[bb] = l2[0] + l2[1];
        ovv[bb] = o2[0] + o2[1];
      }
      // deferred h-reduction: 8 independent butterfly chains, interleaved
#pragma unroll
      for (int bb = 0; bb < 4; ++bb) {
        lvv[bb] += __shfl_xor(lvv[bb], 16);
        ovv[bb] += __shfl_xor(ovv[bb], 16);
      }
#pragma unroll
      for (int bb = 0; bb < 4; ++bb) {
        lvv[bb] += __shfl_xor(lvv[bb], 32);
        ovv[bb] += __shfl_xor(ovv[bb], 32);
      }
      if (h == 0) {
#pragma unroll
        for (int bb = 0; bb < 4; ++bb) {
          const int ri = (w * 16 + b4 + bb) * 16 + il;   // per-wave slot
          if (NSEG == 1 || seg == 0) {
            red[ri] = lvv[bb]; red[1024 + ri] = ovv[bb];
          } else {
            red[ri] += lvv[bb]; red[1024 + ri] += ovv[bb];
          }
        }
      }
    }
  }

  __syncthreads();
  {
    const int b = t >> 4, ii = t & 15;
    float lsum = 0.f, osum = 0.f;
#pragma unroll
    for (int ww = 0; ww < 4; ++ww) {
      lsum += red[(ww * 16 + b) * 16 + ii];
      osum += red[1024 + (ww * 16 + b) * 16 + ii];
    }
    const int outidx = (js * NB + b) * NN + i0 + ii;
    part_l[outidx] = lsum;
    part_o[outidx] = osum;
  }
}

// ---------------------------------------------------------------------------
// Kernel 3: deterministic combine of the JSPLIT partial sums; out = Σo / Σl.
// ---------------------------------------------------------------------------
template <int JSPLIT>
__global__ void combine_kernel(const float* __restrict__ part_l,
                               const float* __restrict__ part_o,
                               float* __restrict__ out) {
  const int id = blockIdx.x * 256 + threadIdx.x;  // b*NN + i
  float l = 0.f, o = 0.f;
#pragma unroll
  for (int js = 0; js < JSPLIT; ++js) {
    l += part_l[js * (NB * NN) + id];
    o += part_o[js * (NB * NN) + id];
  }
  out[id] = o / l;
}

extern "C" void kernel_launch(void* const* d_in, const int* in_sizes, int n_in,
                              void* d_out, int out_size, void* d_ws, size_t ws_size,
                              hipStream_t stream) {
  const float* x   = (const float*)d_in[0];
  const float* q_w = (const float*)d_in[1];
  const float* q_b = (const float*)d_in[2];
  const float* k_w = (const float*)d_in[3];
  const float* k_b = (const float*)d_in[4];
  const float* pe  = (const float*)d_in[5];
  float* out = (float*)d_out;

  char* ws = (char*)d_ws;
  u16*   Qbh    = (u16*)(ws);                                    // 1 MB
  u16*   Kbh    = (u16*)(ws + (1u << 20));                       // 1 MB
  float* A2     = (float*)(ws + (2u << 20));                     // 16 KB
  float* B2     = (float*)(ws + (2u << 20) + (16u << 10));       // 16 KB
  float* c2p    = (float*)(ws + (2u << 20) + (32u << 10));       // 64 B
  float* part_l = (float*)(ws + (2u << 20) + (48u << 10));

  precomp_kernel<<<NN / 4, 256, 0, stream>>>(q_w, q_b, k_w, k_b, pe,
                                             Qbh, Kbh, A2, B2, c2p);

  const size_t base = (size_t)(2u << 20) + (48u << 10);
  const size_t need16 = base + 2 * (size_t)16 * NB * NN * 4;  // ~10.4 MB
  if (ws_size >= need16) {
    float* part_o = (float*)(ws + base + (size_t)16 * NB * NN * 4);
    attn_main<16><<<dim3(NN / 16, 16), 256, 0, stream>>>(
        x, Qbh, Kbh, A2, B2, c2p, part_l, part_o);
    combine_kernel<16><<<(NB * NN) / 256, 256, 0, stream>>>(part_l, part_o, out);
  } else {
    float* part_o = (float*)(ws + base + (size_t)8 * NB * NN * 4);
    attn_main<8><<<dim3(NN / 16, 8), 256, 0, stream>>>(
        x, Qbh, Kbh, A2, B2, c2p, part_l, part_o);
    combine_kernel<8><<<(NB * NN) / 256, 256, 0, stream>>>(part_l, part_o, out);
  }
}